// Round 1
// baseline (11.610 us; speedup 1.0000x reference)
//
#include <hip/hip_runtime.h>

// DipolePredictorE3NN: fused TP-scalar-gate + mean-pool + 3->128->3 MLP.
// One block per batch element b. adj_mat (d_in[2]) is unused by the reference.

#define BLOCK 256
#define NSC 7
#define HID 128

__global__ __launch_bounds__(BLOCK) void dipole_e3nn_kernel(
    const float* __restrict__ feats,   // [B, N, 7]
    const float* __restrict__ coors,   // [B, N, 3]
    const float* __restrict__ W_tp,    // [7]
    const float* __restrict__ W1,      // [128, 3] row-major
    const float* __restrict__ b1,      // [128]
    const float* __restrict__ W2,      // [3, 128] row-major
    const float* __restrict__ b2,      // [3]
    float* __restrict__ out,           // [B, 3]
    int N)
{
    const int b = blockIdx.x;
    const int t = threadIdx.x;
    const int wave = t >> 6;
    const int lane = t & 63;

    // broadcast-load the 7 TP weights (scalar loads, cached)
    const float w0 = W_tp[0], w1 = W_tp[1], w2 = W_tp[2], w3 = W_tp[3],
                w4 = W_tp[4], w5 = W_tp[5], w6 = W_tp[6];

    const float* fb = feats + (size_t)b * N * NSC;
    const float* cb = coors + (size_t)b * N * 3;

    float ax = 0.f, ay = 0.f, az = 0.f;
    for (int n = t; n < N; n += BLOCK) {
        const float* f = fb + n * NSC;
        float s = f[0]*w0 + f[1]*w1 + f[2]*w2 + f[3]*w3
                + f[4]*w4 + f[5]*w5 + f[6]*w6;
        const float* c = cb + n * 3;
        ax += s * c[0];
        ay += s * c[1];
        az += s * c[2];
    }

    // ---- block reduction of (ax, ay, az) ----
    __shared__ float red[3][4];
    __shared__ float ge[3];
    #pragma unroll
    for (int off = 32; off > 0; off >>= 1) {
        ax += __shfl_down(ax, off);
        ay += __shfl_down(ay, off);
        az += __shfl_down(az, off);
    }
    if (lane == 0) { red[0][wave] = ax; red[1][wave] = ay; red[2][wave] = az; }
    __syncthreads();
    if (t == 0) {
        // alpha = 1/sqrt(7) rounded to f32; mean = /N (N=512 exact)
        const float alpha = 0.3779644730092272f;
        const float scale = alpha / (float)N;
        ge[0] = (red[0][0] + red[0][1] + red[0][2] + red[0][3]) * scale;
        ge[1] = (red[1][0] + red[1][1] + red[1][2] + red[1][3]) * scale;
        ge[2] = (red[2][0] + red[2][1] + red[2][2] + red[2][3]) * scale;
    }
    __syncthreads();  // ge visible; red free for reuse

    // ---- MLP: h = relu(ge @ W1^T + b1); out = h @ W2^T + b2 ----
    float p0 = 0.f, p1 = 0.f, p2 = 0.f;
    if (t < HID) {
        float h = ge[0] * W1[t*3 + 0] + ge[1] * W1[t*3 + 1] + ge[2] * W1[t*3 + 2] + b1[t];
        h = fmaxf(h, 0.f);
        p0 = h * W2[0*HID + t];
        p1 = h * W2[1*HID + t];
        p2 = h * W2[2*HID + t];
    }
    #pragma unroll
    for (int off = 32; off > 0; off >>= 1) {
        p0 += __shfl_down(p0, off);
        p1 += __shfl_down(p1, off);
        p2 += __shfl_down(p2, off);
    }
    if (lane == 0) { red[0][wave] = p0; red[1][wave] = p1; red[2][wave] = p2; }
    __syncthreads();
    if (t == 0) {
        out[b*3 + 0] = red[0][0] + red[0][1] + red[0][2] + red[0][3] + b2[0];
        out[b*3 + 1] = red[1][0] + red[1][1] + red[1][2] + red[1][3] + b2[1];
        out[b*3 + 2] = red[2][0] + red[2][1] + red[2][2] + red[2][3] + b2[2];
    }
}

extern "C" void kernel_launch(void* const* d_in, const int* in_sizes, int n_in,
                              void* d_out, int out_size, void* d_ws, size_t ws_size,
                              hipStream_t stream) {
    // setup_inputs order: feats, coors, adj_mat, W_tp, W1, b1, W2, b2
    const float* feats = (const float*)d_in[0];
    const float* coors = (const float*)d_in[1];
    // d_in[2] = adj_mat (unused by reference)
    const float* W_tp  = (const float*)d_in[3];
    const float* W1    = (const float*)d_in[4];
    const float* b1    = (const float*)d_in[5];
    const float* W2    = (const float*)d_in[6];
    const float* b2    = (const float*)d_in[7];
    float* out = (float*)d_out;

    const int B = 1024;
    const int N = 512;

    dipole_e3nn_kernel<<<B, BLOCK, 0, stream>>>(feats, coors, W_tp, W1, b1, W2, b2, out, N);
}

// Round 2
// 9.769 us; speedup vs baseline: 1.1884x; 1.1884x over previous
//
#include <hip/hip_runtime.h>

// DipolePredictorE3NN: fused TP-scalar-gate + mean-pool + 3->128->3 MLP.
// One block per batch element b, 128 threads; each thread owns 4 rows so all
// global loads are float4 (4 rows x 7 feats = 7 float4; 4 rows x 3 coors = 3 float4).
// adj_mat (d_in[2]) is unused by the reference.

#define BLOCK 128
#define NSC 7
#define HID 128

__global__ __launch_bounds__(BLOCK) void dipole_e3nn_kernel(
    const float* __restrict__ feats,   // [B, N, 7]
    const float* __restrict__ coors,   // [B, N, 3]
    const float* __restrict__ W_tp,    // [7]
    const float* __restrict__ W1,      // [128, 3] row-major
    const float* __restrict__ b1,      // [128]
    const float* __restrict__ W2,      // [3, 128] row-major
    const float* __restrict__ b2,      // [3]
    float* __restrict__ out)           // [B, 3]
{
    const int b = blockIdx.x;
    const int t = threadIdx.x;          // 0..127, owns rows 4t..4t+3
    const int wave = t >> 6;
    const int lane = t & 63;

    const float w0 = W_tp[0], w1 = W_tp[1], w2 = W_tp[2], w3 = W_tp[3],
                w4 = W_tp[4], w5 = W_tp[5], w6 = W_tp[6];

    // feats block = 512*7 = 3584 floats = 896 float4; 7 float4 per thread.
    const float4* fq = (const float4*)feats + (size_t)b * 896 + t * 7;
    // coors block = 512*3 = 1536 floats = 384 float4; 3 float4 per thread.
    const float4* cq = (const float4*)coors + (size_t)b * 384 + t * 3;

    float f[28];
    *(float4*)&f[0]  = fq[0];
    *(float4*)&f[4]  = fq[1];
    *(float4*)&f[8]  = fq[2];
    *(float4*)&f[12] = fq[3];
    *(float4*)&f[16] = fq[4];
    *(float4*)&f[20] = fq[5];
    *(float4*)&f[24] = fq[6];
    float c[12];
    *(float4*)&c[0] = cq[0];
    *(float4*)&c[4] = cq[1];
    *(float4*)&c[8] = cq[2];

    float s0 = f[0]*w0 + f[1]*w1 + f[2]*w2 + f[3]*w3 + f[4]*w4 + f[5]*w5 + f[6]*w6;
    float s1 = f[7]*w0 + f[8]*w1 + f[9]*w2 + f[10]*w3 + f[11]*w4 + f[12]*w5 + f[13]*w6;
    float s2 = f[14]*w0 + f[15]*w1 + f[16]*w2 + f[17]*w3 + f[18]*w4 + f[19]*w5 + f[20]*w6;
    float s3 = f[21]*w0 + f[22]*w1 + f[23]*w2 + f[24]*w3 + f[25]*w4 + f[26]*w5 + f[27]*w6;

    float ax = s0*c[0] + s1*c[3] + s2*c[6] + s3*c[9];
    float ay = s0*c[1] + s1*c[4] + s2*c[7] + s3*c[10];
    float az = s0*c[2] + s1*c[5] + s2*c[8] + s3*c[11];

    // ---- block reduction of (ax, ay, az) over 2 waves ----
    __shared__ float red[3][2];
    __shared__ float ge[3];
    #pragma unroll
    for (int off = 32; off > 0; off >>= 1) {
        ax += __shfl_down(ax, off);
        ay += __shfl_down(ay, off);
        az += __shfl_down(az, off);
    }
    if (lane == 0) { red[0][wave] = ax; red[1][wave] = ay; red[2][wave] = az; }
    __syncthreads();
    if (t == 0) {
        const float alpha = 0.3779644730092272f;   // 1/sqrt(7)
        const float scale = alpha / 512.0f;        // mean over N=512 (exact)
        ge[0] = (red[0][0] + red[0][1]) * scale;
        ge[1] = (red[1][0] + red[1][1]) * scale;
        ge[2] = (red[2][0] + red[2][1]) * scale;
    }
    __syncthreads();

    // ---- MLP: h = relu(ge @ W1^T + b1); out = h @ W2^T + b2 ----
    float h = ge[0] * W1[t*3 + 0] + ge[1] * W1[t*3 + 1] + ge[2] * W1[t*3 + 2] + b1[t];
    h = fmaxf(h, 0.f);
    float p0 = h * W2[0*HID + t];
    float p1 = h * W2[1*HID + t];
    float p2 = h * W2[2*HID + t];

    #pragma unroll
    for (int off = 32; off > 0; off >>= 1) {
        p0 += __shfl_down(p0, off);
        p1 += __shfl_down(p1, off);
        p2 += __shfl_down(p2, off);
    }
    if (lane == 0) { red[0][wave] = p0; red[1][wave] = p1; red[2][wave] = p2; }
    __syncthreads();
    if (t == 0) {
        out[b*3 + 0] = red[0][0] + red[0][1] + b2[0];
        out[b*3 + 1] = red[1][0] + red[1][1] + b2[1];
        out[b*3 + 2] = red[2][0] + red[2][1] + b2[2];
    }
}

extern "C" void kernel_launch(void* const* d_in, const int* in_sizes, int n_in,
                              void* d_out, int out_size, void* d_ws, size_t ws_size,
                              hipStream_t stream) {
    // setup_inputs order: feats, coors, adj_mat, W_tp, W1, b1, W2, b2
    const float* feats = (const float*)d_in[0];
    const float* coors = (const float*)d_in[1];
    // d_in[2] = adj_mat (unused by reference)
    const float* W_tp  = (const float*)d_in[3];
    const float* W1    = (const float*)d_in[4];
    const float* b1    = (const float*)d_in[5];
    const float* W2    = (const float*)d_in[6];
    const float* b2    = (const float*)d_in[7];
    float* out = (float*)d_out;

    const int B = 1024;
    dipole_e3nn_kernel<<<B, BLOCK, 0, stream>>>(feats, coors, W_tp, W1, b1, W2, b2, out);
}